// Round 20
// baseline (114.759 us; speedup 1.0000x reference)
//
#include <hip/hip_runtime.h>
#include <hip/hip_cooperative_groups.h>

#define BB 8
#define NN 4096
#define CCH 512
#define KK 32
#define CLS 21
#define BN_EPS 1e-3f

#define CHUNK 128
#define NBLK (NN / CHUNK)   // 32

typedef _Float16 f16;
typedef _Float16 f16x8 __attribute__((ext_vector_type(8)));
typedef float f32x4 __attribute__((ext_vector_type(4)));

#define WP 136   // wexch row pitch in f16 (272 B)

// ws layout (floats)
#define WS_P    0                                  // [NBLK][BB][CCH][KK] fp32 partials
#define WS_WSP  (NBLK * BB * CCH * KK)             // 4194304  [NBLK][BB][KK]
#define WS_ENC  (WS_WSP + NBLK * BB * KK)          // 4202496  [BB][CCH]
#define WS_END  (WS_ENC + BB * CCH)

template <int CTRL>
__device__ __forceinline__ float dpp_add(float v) {
    int r = __builtin_amdgcn_update_dpp(0, __builtin_bit_cast(int, v),
                                        CTRL, 0xF, 0xF, true);
    return v + __builtin_bit_cast(float, r);
}
template <int CTRL>
__device__ __forceinline__ float dpp_max(float v) {
    int r = __builtin_amdgcn_update_dpp(0, __builtin_bit_cast(int, v),
                                        CTRL, 0xF, 0xF, true);
    return fmaxf(v, __builtin_bit_cast(float, r));
}
__device__ __forceinline__ float rowsum16(float v) {
    v = dpp_add<0x128>(v); v = dpp_add<0x124>(v);
    v = dpp_add<0x122>(v); v = dpp_add<0x121>(v);
    return v;
}
__device__ __forceinline__ float rowmax16(float v) {
    v = dpp_max<0x128>(v); v = dpp_max<0x124>(v);
    v = dpp_max<0x122>(v); v = dpp_max<0x121>(v);
    return v;
}

// ---------------------------------------------------------------------------
// Shared LDS for enc (+reduce reuses redtmp region)
// ---------------------------------------------------------------------------
struct EncLds {
    f16   cwL[2048 * 8];     // 32768 B
    f16   wexch[32 * WP];    //  8704 B
    float wsq[8][KK];        //  1024 B
    float csqL[KK];
    float nsfL[KK];
    float redtmp[16][KK];    //  2048 B (csq parts; reduce-phase wsum reuses row 0)
};

// ---------------------------------------------------------------------------
// enc body: 8 waves, 128-row chunk. csq computed from cwL (LDS), not global.
// ---------------------------------------------------------------------------
__device__ __forceinline__ void enc_body(
    const float* __restrict__ x, const float* __restrict__ cw,
    const float* __restrict__ sf, float* __restrict__ ws,
    EncLds& S, int chunk, int b, int t)
{
    const int w = t >> 6, l = t & 63, a = l & 15, g = l >> 4;
    const int n0 = chunk * CHUNK;

    // ---- stage cwL in B-fragment layout (from global cw, L3-hot) ----
#pragma unroll
    for (int si = 0; si < 4; ++si) {
        const int s     = si * 512 + t;        // 0..2047
        const int lane  = s & 63;
        const int cstep = (s >> 6) & 15;
        const int kt    = s >> 10;
        const int k     = (lane & 15) + 16 * kt;
        const int c0    = cstep * 32 + (lane >> 4) * 8;
        f16x8 v;
#pragma unroll
        for (int i = 0; i < 8; ++i) v[i] = (f16)cw[(c0 + i) * KK + k];
        *reinterpret_cast<f16x8*>(S.cwL + (size_t)s * 8) = v;
    }
    __syncthreads();   // cwL ready

    // ---- csq from cwL: thread (k = t&31, cstep = t>>5) reads 4 f16x8 ----
    {
        const int k = t & 31, cstep = t >> 5;
        const int kt = k >> 4, kb = k & 15;
        float s = 0.f;
#pragma unroll
        for (int l4 = 0; l4 < 4; ++l4) {
            const int lane = (l4 << 4) | kb;
            const f16x8 v = *reinterpret_cast<const f16x8*>(
                S.cwL + ((size_t)(kt * 16 + cstep) * 64 + lane) * 8);
#pragma unroll
            for (int i = 0; i < 8; ++i) {
                const float f = (float)v[i];
                s += f * f;
            }
        }
        S.redtmp[cstep][k] = s;
    }
    __syncthreads();
    if (t < KK) {
        float s = 0.f;
#pragma unroll
        for (int p = 0; p < 16; ++p) s += S.redtmp[p][t];
        S.csqL[t] = s;
        S.nsfL[t] = -sf[t];
    }
    __syncthreads();   // csqL/nsfL ready

    const float csq0 = S.csqL[a], csq1 = S.csqL[a + 16];
    const float nsf0 = S.nsfL[a], nsf1 = S.nsfL[a + 16];

    // ---- cross: wave-local, rows n0+w*16+a; B-frags from LDS ----
    f32x4 d0 = {0.f, 0.f, 0.f, 0.f}, d1 = {0.f, 0.f, 0.f, 0.f};
    float xs = 0.f;
    {
        const float* xrow = x + (size_t)(b * NN + n0 + w * 16 + a) * CCH;
#pragma unroll
        for (int cs = 0; cs < 16; ++cs) {
            const int c0 = cs * 32 + g * 8;
            const float4 u0 = *reinterpret_cast<const float4*>(xrow + c0);
            const float4 u1 = *reinterpret_cast<const float4*>(xrow + c0 + 4);
            xs += u0.x*u0.x + u0.y*u0.y + u0.z*u0.z + u0.w*u0.w
                + u1.x*u1.x + u1.y*u1.y + u1.z*u1.z + u1.w*u1.w;
            const f16x8 af = {(f16)u0.x, (f16)u0.y, (f16)u0.z, (f16)u0.w,
                              (f16)u1.x, (f16)u1.y, (f16)u1.z, (f16)u1.w};
            const f16x8 bf0 = *reinterpret_cast<const f16x8*>(
                S.cwL + ((size_t)cs * 64 + l) * 8);
            const f16x8 bf1 = *reinterpret_cast<const f16x8*>(
                S.cwL + ((size_t)(16 + cs) * 64 + l) * 8);
            d0 = __builtin_amdgcn_mfma_f32_16x16x32_f16(af, bf0, d0, 0, 0, 0);
            d1 = __builtin_amdgcn_mfma_f32_16x16x32_f16(af, bf1, d1, 0, 0, 0);
        }
        xs += __shfl_xor(xs, 16);
        xs += __shfl_xor(xs, 32);
    }

    // ---- softmax: fully in-wave ----
    float wsacc0 = 0.f, wsacc1 = 0.f;
#pragma unroll
    for (int r = 0; r < 4; ++r) {
        const int rho = g * 4 + r;
        const float xsr = __shfl(xs, rho);
        const float l0 = (xsr - 2.f * d0[r] + csq0) * nsf0;
        const float l1 = (xsr - 2.f * d1[r] + csq1) * nsf1;
        const float mx = rowmax16(fmaxf(l0, l1));
        const float e0 = __expf(l0 - mx);
        const float e1 = __expf(l1 - mx);
        const float inv = 1.f / rowsum16(e0 + e1);
        const float w0 = e0 * inv, w1 = e1 * inv;
        wsacc0 += w0; wsacc1 += w1;
        S.wexch[(a     ) * WP + w * 16 + rho] = (f16)w0;
        S.wexch[(a + 16) * WP + w * 16 + rho] = (f16)w1;
    }
    wsacc0 += __shfl_xor(wsacc0, 16); wsacc0 += __shfl_xor(wsacc0, 32);
    wsacc1 += __shfl_xor(wsacc1, 16); wsacc1 += __shfl_xor(wsacc1, 32);
    if (l < 16) { S.wsq[w][l] = wsacc0; S.wsq[w][l + 16] = wsacc1; }

    __syncthreads();   // wexch/wsq ready

    // ---- wx: A[k][n] from wexch, B[n][c] gathered from global; 64 c/wave ----
    f32x4 acc[4][2];
#pragma unroll
    for (int ct = 0; ct < 4; ++ct)
#pragma unroll
        for (int kt = 0; kt < 2; ++kt) acc[ct][kt] = (f32x4){0.f, 0.f, 0.f, 0.f};

    const int c0 = w * 64;
#pragma unroll
    for (int sq2 = 0; sq2 < 4; ++sq2) {
        const f16x8 a0 = *reinterpret_cast<const f16x8*>(
            &S.wexch[(a     ) * WP + sq2 * 32 + g * 8]);
        const f16x8 a1 = *reinterpret_cast<const f16x8*>(
            &S.wexch[(a + 16) * WP + sq2 * 32 + g * 8]);
        const float* xb = x + (size_t)(b * NN + n0 + sq2 * 32 + g * 8) * CCH;
#pragma unroll
        for (int ct = 0; ct < 4; ++ct) {
            const int c = c0 + ct * 16 + a;
            f16x8 B;
#pragma unroll
            for (int i = 0; i < 8; ++i) B[i] = (f16)xb[(size_t)i * CCH + c];
            acc[ct][0] = __builtin_amdgcn_mfma_f32_16x16x32_f16(a0, B, acc[ct][0], 0, 0, 0);
            acc[ct][1] = __builtin_amdgcn_mfma_f32_16x16x32_f16(a1, B, acc[ct][1], 0, 0, 0);
        }
    }

    // ---- store partials ----
    {
        float* pp = ws + WS_P + ((size_t)(chunk * BB + b)) * CCH * KK;
#pragma unroll
        for (int ct = 0; ct < 4; ++ct) {
            const int c = c0 + ct * 16 + a;
#pragma unroll
            for (int kt = 0; kt < 2; ++kt)
                *reinterpret_cast<f32x4*>(pp + (size_t)c * KK + kt * 16 + g * 4) = acc[ct][kt];
        }
    }
    if (t < KK) {
        float s = 0.f;
#pragma unroll
        for (int p = 0; p < 8; ++p) s += S.wsq[p][t];
        ws[WS_WSP + ((size_t)chunk * BB + b) * KK + t] = s;
    }
}

// ---------------------------------------------------------------------------
// reduce body: block (cs, b) reduces 16 c; threads t<128 active (f32x4 loads).
// ---------------------------------------------------------------------------
__device__ __forceinline__ void reduce_body(
    float* __restrict__ ws, const float* __restrict__ cw,
    const float* __restrict__ gamma, const float* __restrict__ beta,
    const float* __restrict__ mean, const float* __restrict__ var,
    float* wsum_s, int cs, int b, int t)
{
    if (t < KK) {
        float s0 = 0.f, s1 = 0.f;
        for (int ch = 0; ch < NBLK; ch += 2) {
            s0 += ws[WS_WSP + ((size_t)(ch + 0) * BB + b) * KK + t];
            s1 += ws[WS_WSP + ((size_t)(ch + 1) * BB + b) * KK + t];
        }
        wsum_s[t] = s0 + s1;
    }
    __syncthreads();

    if (t < 128) {
        const int cl = t >> 3;
        const int c  = cs * 16 + cl;
        const int kq = t & 7;
        const float* p = ws + WS_P + ((size_t)b * CCH + c) * KK + kq * 4;
        const size_t stride = (size_t)BB * CCH * KK;

        f32x4 a0 = {0.f, 0.f, 0.f, 0.f}, a1 = {0.f, 0.f, 0.f, 0.f};
        for (int ch = 0; ch < NBLK; ch += 2) {
            a0 += *reinterpret_cast<const f32x4*>(p + (ch + 0) * stride);
            a1 += *reinterpret_cast<const f32x4*>(p + (ch + 1) * stride);
        }
        const f32x4 aa = a0 + a1;

        const float g  = gamma[c] * rsqrtf(var[c] + BN_EPS);
        const float mu = mean[c];
        const float be = beta[c];
        const float4 cv = *reinterpret_cast<const float4*>(cw + c * KK + kq * 4);
        const float4 sv = *reinterpret_cast<const float4*>(&wsum_s[kq * 4]);
        float s = 0.f;
        s += fmaxf((aa[0] - cv.x * sv.x - mu) * g + be, 0.f);
        s += fmaxf((aa[1] - cv.y * sv.y - mu) * g + be, 0.f);
        s += fmaxf((aa[2] - cv.z * sv.z - mu) * g + be, 0.f);
        s += fmaxf((aa[3] - cv.w * sv.w - mu) * g + be, 0.f);
        s += __shfl_xor(s, 1);
        s += __shfl_xor(s, 2);
        s += __shfl_xor(s, 4);
        if (kq == 0) ws[WS_ENC + (size_t)b * CCH + c] = s;
    }
}

// ---------------------------------------------------------------------------
// Cooperative: enc + grid.sync + reduce in one launch. grid (32,8), 512 thr.
// ---------------------------------------------------------------------------
__global__ __launch_bounds__(512, 1) void enc_reduce_coop(
    const float* __restrict__ x, const float* __restrict__ cw,
    const float* __restrict__ sf, const float* __restrict__ gamma,
    const float* __restrict__ beta, const float* __restrict__ mean,
    const float* __restrict__ var, float* __restrict__ ws)
{
    __shared__ EncLds S;
    const int t = threadIdx.x;
    enc_body(x, cw, sf, ws, S, blockIdx.x, blockIdx.y, t);
    cooperative_groups::this_grid().sync();
    reduce_body(ws, cw, gamma, beta, mean, var, S.redtmp[0],
                blockIdx.x, blockIdx.y, t);
}

// ---------------------------------------------------------------------------
// Fallback pair (non-cooperative)
// ---------------------------------------------------------------------------
__global__ __launch_bounds__(512, 2) void enc_only(
    const float* __restrict__ x, const float* __restrict__ cw,
    const float* __restrict__ sf, float* __restrict__ ws)
{
    __shared__ EncLds S;
    enc_body(x, cw, sf, ws, S, blockIdx.x, blockIdx.y, threadIdx.x);
}

__global__ __launch_bounds__(512) void reduce_only(
    float* __restrict__ ws, const float* __restrict__ cw,
    const float* __restrict__ gamma, const float* __restrict__ beta,
    const float* __restrict__ mean, const float* __restrict__ var)
{
    __shared__ float wsum_s[KK];
    reduce_body(ws, cw, gamma, beta, mean, var, wsum_s,
                blockIdx.x, blockIdx.y, threadIdx.x);
}

// ---------------------------------------------------------------------------
// Kernel C: fused attn + scale (+ se in the cc==8 plane) — r19 verbatim.
// ---------------------------------------------------------------------------
__global__ __launch_bounds__(256) void scale_fused(
    const float* __restrict__ x, const float* __restrict__ enc,
    const float* __restrict__ w_enc, const float* __restrict__ b_enc,
    const float* __restrict__ w_se, const float* __restrict__ b_se,
    float* __restrict__ out)
{
    __shared__ float ev[CCH];
    __shared__ float red[4][64];
    __shared__ float attnL[64];

    const int ns = blockIdx.x;
    const int cc = blockIdx.y;
    const int b  = blockIdx.z;
    const int t  = threadIdx.x;

    if (cc == 8) {
        if (ns != 0) return;
        ev[t]       = enc[(size_t)b * CCH + t];
        ev[t + 256] = enc[(size_t)b * CCH + 256 + t];
        __syncthreads();
        if (t < 8 * CLS) {
            const int j = t >> 3, p = t & 7;
            float a = 0.f;
            for (int c = p; c < CCH; c += 8) a += ev[c] * w_se[c * CLS + j];
            a += __shfl_xor(a, 1);
            a += __shfl_xor(a, 2);
            a += __shfl_xor(a, 4);
            if (p == 0)
                out[(size_t)BB * NN * CCH + b * CLS + j] =
                    1.f / (1.f + __expf(-(a + b_se[j])));
        }
        return;
    }

    ev[t]       = enc[(size_t)b * CCH + t];
    ev[t + 256] = enc[(size_t)b * CCH + 256 + t];
    __syncthreads();

    {
        const int c2 = cc * 64 + (t & 63);
        const int p  = t >> 6;
        float a0 = 0.f, a1 = 0.f, a2 = 0.f, a3 = 0.f;
#pragma unroll
        for (int i = 0; i < 128; i += 4) {
            const int c = p * 128 + i;
            a0 += ev[c + 0] * w_enc[(size_t)(c + 0) * CCH + c2];
            a1 += ev[c + 1] * w_enc[(size_t)(c + 1) * CCH + c2];
            a2 += ev[c + 2] * w_enc[(size_t)(c + 2) * CCH + c2];
            a3 += ev[c + 3] * w_enc[(size_t)(c + 3) * CCH + c2];
        }
        red[p][t & 63] = (a0 + a1) + (a2 + a3);
        __syncthreads();
        if (t < 64) {
            const float v = red[0][t] + red[1][t] + red[2][t] + red[3][t]
                          + b_enc[cc * 64 + t];
            attnL[t] = 1.f / (1.f + __expf(-v));
        }
        __syncthreads();
    }

    const int q   = t & 15;
    const int rr0 = t >> 4;
    const f32x4 av = *reinterpret_cast<const f32x4*>(attnL + q * 4);
#pragma unroll 8
    for (int i = 0; i < 32; ++i) {
        const int r = ns * 512 + i * 16 + rr0;
        const size_t off = ((size_t)(b * NN + r)) * CCH + cc * 64 + q * 4;
        const f32x4 xv = *reinterpret_cast<const f32x4*>(x + off);
        __builtin_nontemporal_store(xv * av, reinterpret_cast<f32x4*>(out + off));
    }
}

// ---------------------------------------------------------------------------
extern "C" void kernel_launch(void* const* d_in, const int* in_sizes, int n_in,
                              void* d_out, int out_size, void* d_ws, size_t ws_size,
                              hipStream_t stream)
{
    const float* x     = (const float*)d_in[0];
    const float* cw    = (const float*)d_in[1];
    const float* sf    = (const float*)d_in[2];
    const float* gamma = (const float*)d_in[3];
    const float* beta  = (const float*)d_in[4];
    const float* mean  = (const float*)d_in[5];
    const float* var   = (const float*)d_in[6];
    const float* w_enc = (const float*)d_in[7];
    const float* b_enc = (const float*)d_in[8];
    const float* w_se  = (const float*)d_in[9];
    const float* b_se  = (const float*)d_in[10];
    float* out = (float*)d_out;
    float* ws  = (float*)d_ws;

    void* args[] = {(void*)&x, (void*)&cw, (void*)&sf, (void*)&gamma,
                    (void*)&beta, (void*)&mean, (void*)&var, (void*)&ws};
    hipError_t err = hipLaunchCooperativeKernel(
        (const void*)enc_reduce_coop, dim3(NBLK, BB), dim3(512), args, 0, stream);
    if (err != hipSuccess) {
        enc_only<<<dim3(NBLK, BB), 512, 0, stream>>>(x, cw, sf, ws);
        reduce_only<<<dim3(32, BB), 512, 0, stream>>>(ws, cw, gamma, beta, mean, var);
    }

    scale_fused<<<dim3(8, 9, BB), 256, 0, stream>>>(
        x, ws + WS_ENC, w_enc, b_enc, w_se, b_se, out);
}

// Round 21
// 62.768 us; speedup vs baseline: 1.8283x; 1.8283x over previous
//
#include <hip/hip_runtime.h>

#define BB 8
#define NN 4096
#define CCH 512
#define KK 32
#define CLS 21
#define BN_EPS 1e-3f

#define CHUNK 128
#define NBLK (NN / CHUNK)   // 32

typedef _Float16 f16;
typedef _Float16 f16x8 __attribute__((ext_vector_type(8)));
typedef float f32x4 __attribute__((ext_vector_type(4)));

#define WP 136   // wexch row pitch in f16 (272 B)

// ws layout (floats)
#define WS_P    0                                  // [NBLK][BB][CCH][KK] fp32 partials
#define WS_WSP  (NBLK * BB * CCH * KK)             // 4194304  [NBLK][BB][KK]
#define WS_ENC  (WS_WSP + NBLK * BB * KK)          // 4202496  [BB][CCH]
#define WS_END  (WS_ENC + BB * CCH)

template <int CTRL>
__device__ __forceinline__ float dpp_add(float v) {
    int r = __builtin_amdgcn_update_dpp(0, __builtin_bit_cast(int, v),
                                        CTRL, 0xF, 0xF, true);
    return v + __builtin_bit_cast(float, r);
}
template <int CTRL>
__device__ __forceinline__ float dpp_max(float v) {
    int r = __builtin_amdgcn_update_dpp(0, __builtin_bit_cast(int, v),
                                        CTRL, 0xF, 0xF, true);
    return fmaxf(v, __builtin_bit_cast(float, r));
}
__device__ __forceinline__ float rowsum16(float v) {
    v = dpp_add<0x128>(v); v = dpp_add<0x124>(v);
    v = dpp_add<0x122>(v); v = dpp_add<0x121>(v);
    return v;
}
__device__ __forceinline__ float rowmax16(float v) {
    v = dpp_max<0x128>(v); v = dpp_max<0x124>(v);
    v = dpp_max<0x122>(v); v = dpp_max<0x121>(v);
    return v;
}

// ---------------------------------------------------------------------------
// Kernel A: 8 waves, 128-row chunk, grid (32,8).  r16/r19 structure with a
// depth-2 software pipeline on the cross loop (prefetch cs+1's x while
// computing cs) — keeps ~4 loads in flight per wave instead of 2.
// ---------------------------------------------------------------------------
__global__ __launch_bounds__(512, 2) void enc_mfma(
    const float* __restrict__ x, const float* __restrict__ cw,
    const float* __restrict__ sf, float* __restrict__ ws)
{
    __shared__ f16   cwL[2048 * 8];     // 32768 B
    __shared__ f16   wexch[32 * WP];    //  8704 B
    __shared__ float wsq[8][KK];        //  1024 B
    __shared__ float csqL[KK];
    __shared__ float nsfL[KK];
    __shared__ float redtmp[8][KK];     //  1024 B

    const int t = threadIdx.x;
    const int w = t >> 6, l = t & 63, a = l & 15, g = l >> 4;
    const int chunk = blockIdx.x, b = blockIdx.y;
    const int n0 = chunk * CHUNK;

    // ---- stage cwL in B-fragment layout (from global cw, L3-hot) ----
#pragma unroll
    for (int si = 0; si < 4; ++si) {
        const int s     = si * 512 + t;        // 0..2047
        const int lane  = s & 63;
        const int cstep = (s >> 6) & 15;
        const int kt    = s >> 10;
        const int k     = (lane & 15) + 16 * kt;
        const int c0    = cstep * 32 + (lane >> 4) * 8;
        f16x8 v;
#pragma unroll
        for (int i = 0; i < 8; ++i) v[i] = (f16)cw[(c0 + i) * KK + k];
        *reinterpret_cast<f16x8*>(cwL + (size_t)s * 8) = v;
    }
    // ---- csq partials (from global cw, L2-hot) ----
    if (t < 256) {
        const int k = t & 31, part = t >> 5;
        float s = 0.f;
        for (int c = part * 64; c < part * 64 + 64; ++c) {
            const float v = cw[c * KK + k];
            s += v * v;
        }
        redtmp[part][k] = s;
    }
    __syncthreads();
    if (t < KK) {
        float s = 0.f;
#pragma unroll
        for (int p = 0; p < 8; ++p) s += redtmp[p][t];
        csqL[t] = s;
        nsfL[t] = -sf[t];
    }
    __syncthreads();   // cwL/csqL/nsfL ready

    const float csq0 = csqL[a], csq1 = csqL[a + 16];
    const float nsf0 = nsfL[a], nsf1 = nsfL[a + 16];

    // ---- cross: wave-local, rows n0+w*16+a; depth-2 pipelined loads ----
    f32x4 d0 = {0.f, 0.f, 0.f, 0.f}, d1 = {0.f, 0.f, 0.f, 0.f};
    float xs = 0.f;
    {
        const float* xrow = x + (size_t)(b * NN + n0 + w * 16 + a) * CCH;
        float4 u0 = *reinterpret_cast<const float4*>(xrow + g * 8);
        float4 u1 = *reinterpret_cast<const float4*>(xrow + g * 8 + 4);
#pragma unroll
        for (int cs = 0; cs < 16; ++cs) {
            float4 p0, p1;
            if (cs < 15) {
                const int cn = (cs + 1) * 32 + g * 8;
                p0 = *reinterpret_cast<const float4*>(xrow + cn);
                p1 = *reinterpret_cast<const float4*>(xrow + cn + 4);
            }
            xs += u0.x*u0.x + u0.y*u0.y + u0.z*u0.z + u0.w*u0.w
                + u1.x*u1.x + u1.y*u1.y + u1.z*u1.z + u1.w*u1.w;
            const f16x8 af = {(f16)u0.x, (f16)u0.y, (f16)u0.z, (f16)u0.w,
                              (f16)u1.x, (f16)u1.y, (f16)u1.z, (f16)u1.w};
            const f16x8 bf0 = *reinterpret_cast<const f16x8*>(
                cwL + ((size_t)cs * 64 + l) * 8);
            const f16x8 bf1 = *reinterpret_cast<const f16x8*>(
                cwL + ((size_t)(16 + cs) * 64 + l) * 8);
            d0 = __builtin_amdgcn_mfma_f32_16x16x32_f16(af, bf0, d0, 0, 0, 0);
            d1 = __builtin_amdgcn_mfma_f32_16x16x32_f16(af, bf1, d1, 0, 0, 0);
            u0 = p0; u1 = p1;
        }
        xs += __shfl_xor(xs, 16);
        xs += __shfl_xor(xs, 32);
    }

    // ---- softmax: fully in-wave ----
    float wsacc0 = 0.f, wsacc1 = 0.f;
#pragma unroll
    for (int r = 0; r < 4; ++r) {
        const int rho = g * 4 + r;
        const float xsr = __shfl(xs, rho);
        const float l0 = (xsr - 2.f * d0[r] + csq0) * nsf0;
        const float l1 = (xsr - 2.f * d1[r] + csq1) * nsf1;
        const float mx = rowmax16(fmaxf(l0, l1));
        const float e0 = __expf(l0 - mx);
        const float e1 = __expf(l1 - mx);
        const float inv = 1.f / rowsum16(e0 + e1);
        const float w0 = e0 * inv, w1 = e1 * inv;
        wsacc0 += w0; wsacc1 += w1;
        wexch[(a     ) * WP + w * 16 + rho] = (f16)w0;
        wexch[(a + 16) * WP + w * 16 + rho] = (f16)w1;
    }
    wsacc0 += __shfl_xor(wsacc0, 16); wsacc0 += __shfl_xor(wsacc0, 32);
    wsacc1 += __shfl_xor(wsacc1, 16); wsacc1 += __shfl_xor(wsacc1, 32);
    if (l < 16) { wsq[w][l] = wsacc0; wsq[w][l + 16] = wsacc1; }

    __syncthreads();   // wexch/wsq ready

    // ---- wx: A[k][n] from wexch, B[n][c] gathered from global; 64 c/wave ----
    f32x4 acc[4][2];
#pragma unroll
    for (int ct = 0; ct < 4; ++ct)
#pragma unroll
        for (int kt = 0; kt < 2; ++kt) acc[ct][kt] = (f32x4){0.f, 0.f, 0.f, 0.f};

    const int c0 = w * 64;
#pragma unroll
    for (int sq2 = 0; sq2 < 4; ++sq2) {
        const f16x8 a0 = *reinterpret_cast<const f16x8*>(
            &wexch[(a     ) * WP + sq2 * 32 + g * 8]);
        const f16x8 a1 = *reinterpret_cast<const f16x8*>(
            &wexch[(a + 16) * WP + sq2 * 32 + g * 8]);
        const float* xb = x + (size_t)(b * NN + n0 + sq2 * 32 + g * 8) * CCH;
#pragma unroll
        for (int ct = 0; ct < 4; ++ct) {
            const int c = c0 + ct * 16 + a;
            f16x8 B;
#pragma unroll
            for (int i = 0; i < 8; ++i) B[i] = (f16)xb[(size_t)i * CCH + c];
            acc[ct][0] = __builtin_amdgcn_mfma_f32_16x16x32_f16(a0, B, acc[ct][0], 0, 0, 0);
            acc[ct][1] = __builtin_amdgcn_mfma_f32_16x16x32_f16(a1, B, acc[ct][1], 0, 0, 0);
        }
    }

    // ---- store partials ----
    {
        float* pp = ws + WS_P + ((size_t)(chunk * BB + b)) * CCH * KK;
#pragma unroll
        for (int ct = 0; ct < 4; ++ct) {
            const int c = c0 + ct * 16 + a;
#pragma unroll
            for (int kt = 0; kt < 2; ++kt)
                *reinterpret_cast<f32x4*>(pp + (size_t)c * KK + kt * 16 + g * 4) = acc[ct][kt];
        }
    }
    if (t < KK) {
        float s = 0.f;
#pragma unroll
        for (int p = 0; p < 8; ++p) s += wsq[p][t];
        ws[WS_WSP + ((size_t)chunk * BB + b) * KK + t] = s;
    }
}

// ---------------------------------------------------------------------------
// Kernel R: reduce partials + enc -> BN -> ReLU -> sum_k => encv
// ---------------------------------------------------------------------------
__global__ __launch_bounds__(256) void reduce_encv(
    float* __restrict__ ws, const float* __restrict__ cw,
    const float* __restrict__ gamma, const float* __restrict__ beta,
    const float* __restrict__ mean, const float* __restrict__ var)
{
    __shared__ float wsum_s[KK];
    const int b  = blockIdx.y;
    const int cs = blockIdx.x;
    const int t  = threadIdx.x;

    if (t < KK) {
        float s0 = 0.f, s1 = 0.f;
        for (int ch = 0; ch < NBLK; ch += 2) {
            s0 += ws[WS_WSP + ((size_t)(ch + 0) * BB + b) * KK + t];
            s1 += ws[WS_WSP + ((size_t)(ch + 1) * BB + b) * KK + t];
        }
        wsum_s[t] = s0 + s1;
    }
    __syncthreads();

    const int cl = t >> 3;
    const int c  = cs * 32 + cl;
    const int kq = t & 7;
    const float* p = ws + WS_P + ((size_t)b * CCH + c) * KK + kq * 4;
    const size_t stride = (size_t)BB * CCH * KK;

    f32x4 a0 = {0.f, 0.f, 0.f, 0.f}, a1 = {0.f, 0.f, 0.f, 0.f};
    for (int ch = 0; ch < NBLK; ch += 2) {
        a0 += *reinterpret_cast<const f32x4*>(p + (ch + 0) * stride);
        a1 += *reinterpret_cast<const f32x4*>(p + (ch + 1) * stride);
    }
    const f32x4 aa = a0 + a1;

    const float g  = gamma[c] * rsqrtf(var[c] + BN_EPS);
    const float mu = mean[c];
    const float be = beta[c];
    const float4 cv = *reinterpret_cast<const float4*>(cw + c * KK + kq * 4);
    const float4 sv = *reinterpret_cast<const float4*>(&wsum_s[kq * 4]);
    float s = 0.f;
    s += fmaxf((aa[0] - cv.x * sv.x - mu) * g + be, 0.f);
    s += fmaxf((aa[1] - cv.y * sv.y - mu) * g + be, 0.f);
    s += fmaxf((aa[2] - cv.z * sv.z - mu) * g + be, 0.f);
    s += fmaxf((aa[3] - cv.w * sv.w - mu) * g + be, 0.f);
    s += __shfl_xor(s, 1);
    s += __shfl_xor(s, 2);
    s += __shfl_xor(s, 4);
    if (kq == 0) ws[WS_ENC + (size_t)b * CCH + c] = s;
}

// ---------------------------------------------------------------------------
// Kernel C: fused attn + scale (+ se in the cc==8 plane) — r19 verbatim.
// ---------------------------------------------------------------------------
__global__ __launch_bounds__(256) void scale_fused(
    const float* __restrict__ x, const float* __restrict__ enc,
    const float* __restrict__ w_enc, const float* __restrict__ b_enc,
    const float* __restrict__ w_se, const float* __restrict__ b_se,
    float* __restrict__ out)
{
    __shared__ float ev[CCH];
    __shared__ float red[4][64];
    __shared__ float attnL[64];

    const int ns = blockIdx.x;
    const int cc = blockIdx.y;
    const int b  = blockIdx.z;
    const int t  = threadIdx.x;

    if (cc == 8) {
        if (ns != 0) return;
        ev[t]       = enc[(size_t)b * CCH + t];
        ev[t + 256] = enc[(size_t)b * CCH + 256 + t];
        __syncthreads();
        if (t < 8 * CLS) {
            const int j = t >> 3, p = t & 7;
            float a = 0.f;
            for (int c = p; c < CCH; c += 8) a += ev[c] * w_se[c * CLS + j];
            a += __shfl_xor(a, 1);
            a += __shfl_xor(a, 2);
            a += __shfl_xor(a, 4);
            if (p == 0)
                out[(size_t)BB * NN * CCH + b * CLS + j] =
                    1.f / (1.f + __expf(-(a + b_se[j])));
        }
        return;
    }

    ev[t]       = enc[(size_t)b * CCH + t];
    ev[t + 256] = enc[(size_t)b * CCH + 256 + t];
    __syncthreads();

    // ---- attn head for c2 = cc*64 + (t&63); 4-way row-part split ----
    {
        const int c2 = cc * 64 + (t & 63);
        const int p  = t >> 6;
        float a0 = 0.f, a1 = 0.f, a2 = 0.f, a3 = 0.f;
#pragma unroll
        for (int i = 0; i < 128; i += 4) {
            const int c = p * 128 + i;
            a0 += ev[c + 0] * w_enc[(size_t)(c + 0) * CCH + c2];
            a1 += ev[c + 1] * w_enc[(size_t)(c + 1) * CCH + c2];
            a2 += ev[c + 2] * w_enc[(size_t)(c + 2) * CCH + c2];
            a3 += ev[c + 3] * w_enc[(size_t)(c + 3) * CCH + c2];
        }
        red[p][t & 63] = (a0 + a1) + (a2 + a3);
        __syncthreads();
        if (t < 64) {
            const float v = red[0][t] + red[1][t] + red[2][t] + red[3][t]
                          + b_enc[cc * 64 + t];
            attnL[t] = 1.f / (1.f + __expf(-v));
        }
        __syncthreads();
    }

    // ---- scale 512 rows x 64 c ----
    const int q   = t & 15;          // c-quad
    const int rr0 = t >> 4;          // row 0..15 (stride 16)
    const f32x4 av = *reinterpret_cast<const f32x4*>(attnL + q * 4);
#pragma unroll 8
    for (int i = 0; i < 32; ++i) {
        const int r = ns * 512 + i * 16 + rr0;
        const size_t off = ((size_t)(b * NN + r)) * CCH + cc * 64 + q * 4;
        const f32x4 xv = *reinterpret_cast<const f32x4*>(x + off);
        __builtin_nontemporal_store(xv * av, reinterpret_cast<f32x4*>(out + off));
    }
}

// ---------------------------------------------------------------------------
extern "C" void kernel_launch(void* const* d_in, const int* in_sizes, int n_in,
                              void* d_out, int out_size, void* d_ws, size_t ws_size,
                              hipStream_t stream)
{
    const float* x     = (const float*)d_in[0];
    const float* cw    = (const float*)d_in[1];
    const float* sf    = (const float*)d_in[2];
    const float* gamma = (const float*)d_in[3];
    const float* beta  = (const float*)d_in[4];
    const float* mean  = (const float*)d_in[5];
    const float* var   = (const float*)d_in[6];
    const float* w_enc = (const float*)d_in[7];
    const float* b_enc = (const float*)d_in[8];
    const float* w_se  = (const float*)d_in[9];
    const float* b_se  = (const float*)d_in[10];
    float* out = (float*)d_out;
    float* ws  = (float*)d_ws;

    enc_mfma<<<dim3(NBLK, BB), 512, 0, stream>>>(x, cw, sf, ws);
    reduce_encv<<<dim3(16, BB), 256, 0, stream>>>(ws, cw, gamma, beta, mean, var);
    scale_fused<<<dim3(8, 9, BB), 256, 0, stream>>>(
        x, ws + WS_ENC, w_enc, b_enc, w_se, b_se, out);
}

// Round 22
// 59.935 us; speedup vs baseline: 1.9147x; 1.0473x over previous
//
#include <hip/hip_runtime.h>

#define BB 8
#define NN 4096
#define CCH 512
#define KK 32
#define CLS 21
#define BN_EPS 1e-3f

#define CHUNK 128
#define NBLK (NN / CHUNK)   // 32

typedef _Float16 f16;
typedef _Float16 f16x4 __attribute__((ext_vector_type(4)));
typedef _Float16 f16x8 __attribute__((ext_vector_type(8)));
typedef float f32x4 __attribute__((ext_vector_type(4)));

#define WP 136   // wexch row pitch in f16 (272 B)

// ws layout (floats).  Partials are f16 now: NBLK*BB*CCH*KK f16 = 2097152 floats.
#define WS_P    0
#define WS_WSP  (NBLK * BB * CCH * KK / 2)         // 2097152  [NBLK][BB][KK] f32
#define WS_ENC  (WS_WSP + NBLK * BB * KK)          // 2105344  [BB][CCH] f32
#define WS_END  (WS_ENC + BB * CCH)

template <int CTRL>
__device__ __forceinline__ float dpp_add(float v) {
    int r = __builtin_amdgcn_update_dpp(0, __builtin_bit_cast(int, v),
                                        CTRL, 0xF, 0xF, true);
    return v + __builtin_bit_cast(float, r);
}
template <int CTRL>
__device__ __forceinline__ float dpp_max(float v) {
    int r = __builtin_amdgcn_update_dpp(0, __builtin_bit_cast(int, v),
                                        CTRL, 0xF, 0xF, true);
    return fmaxf(v, __builtin_bit_cast(float, r));
}
__device__ __forceinline__ float rowsum16(float v) {
    v = dpp_add<0x128>(v); v = dpp_add<0x124>(v);
    v = dpp_add<0x122>(v); v = dpp_add<0x121>(v);
    return v;
}
__device__ __forceinline__ float rowmax16(float v) {
    v = dpp_max<0x128>(v); v = dpp_max<0x124>(v);
    v = dpp_max<0x122>(v); v = dpp_max<0x121>(v);
    return v;
}

// ---------------------------------------------------------------------------
// Kernel A: 8 waves, 128-row chunk, grid (32,8).  r21 structure; partials
// stored as f16 (halves the partial tensor round-trip).
// ---------------------------------------------------------------------------
__global__ __launch_bounds__(512, 2) void enc_mfma(
    const float* __restrict__ x, const float* __restrict__ cw,
    const float* __restrict__ sf, float* __restrict__ ws)
{
    __shared__ f16   cwL[2048 * 8];     // 32768 B
    __shared__ f16   wexch[32 * WP];    //  8704 B
    __shared__ float wsq[8][KK];        //  1024 B
    __shared__ float csqL[KK];
    __shared__ float nsfL[KK];
    __shared__ float redtmp[8][KK];     //  1024 B

    const int t = threadIdx.x;
    const int w = t >> 6, l = t & 63, a = l & 15, g = l >> 4;
    const int chunk = blockIdx.x, b = blockIdx.y;
    const int n0 = chunk * CHUNK;

    // ---- stage cwL in B-fragment layout (from global cw, L3-hot) ----
#pragma unroll
    for (int si = 0; si < 4; ++si) {
        const int s     = si * 512 + t;        // 0..2047
        const int lane  = s & 63;
        const int cstep = (s >> 6) & 15;
        const int kt    = s >> 10;
        const int k     = (lane & 15) + 16 * kt;
        const int c0    = cstep * 32 + (lane >> 4) * 8;
        f16x8 v;
#pragma unroll
        for (int i = 0; i < 8; ++i) v[i] = (f16)cw[(c0 + i) * KK + k];
        *reinterpret_cast<f16x8*>(cwL + (size_t)s * 8) = v;
    }
    // ---- csq partials (from global cw, L2-hot) ----
    if (t < 256) {
        const int k = t & 31, part = t >> 5;
        float s = 0.f;
        for (int c = part * 64; c < part * 64 + 64; ++c) {
            const float v = cw[c * KK + k];
            s += v * v;
        }
        redtmp[part][k] = s;
    }
    __syncthreads();
    if (t < KK) {
        float s = 0.f;
#pragma unroll
        for (int p = 0; p < 8; ++p) s += redtmp[p][t];
        csqL[t] = s;
        nsfL[t] = -sf[t];
    }
    __syncthreads();   // cwL/csqL/nsfL ready

    const float csq0 = csqL[a], csq1 = csqL[a + 16];
    const float nsf0 = nsfL[a], nsf1 = nsfL[a + 16];

    // ---- cross: wave-local, rows n0+w*16+a; depth-2 pipelined loads ----
    f32x4 d0 = {0.f, 0.f, 0.f, 0.f}, d1 = {0.f, 0.f, 0.f, 0.f};
    float xs = 0.f;
    {
        const float* xrow = x + (size_t)(b * NN + n0 + w * 16 + a) * CCH;
        float4 u0 = *reinterpret_cast<const float4*>(xrow + g * 8);
        float4 u1 = *reinterpret_cast<const float4*>(xrow + g * 8 + 4);
#pragma unroll
        for (int cs = 0; cs < 16; ++cs) {
            float4 p0, p1;
            if (cs < 15) {
                const int cn = (cs + 1) * 32 + g * 8;
                p0 = *reinterpret_cast<const float4*>(xrow + cn);
                p1 = *reinterpret_cast<const float4*>(xrow + cn + 4);
            }
            xs += u0.x*u0.x + u0.y*u0.y + u0.z*u0.z + u0.w*u0.w
                + u1.x*u1.x + u1.y*u1.y + u1.z*u1.z + u1.w*u1.w;
            const f16x8 af = {(f16)u0.x, (f16)u0.y, (f16)u0.z, (f16)u0.w,
                              (f16)u1.x, (f16)u1.y, (f16)u1.z, (f16)u1.w};
            const f16x8 bf0 = *reinterpret_cast<const f16x8*>(
                cwL + ((size_t)cs * 64 + l) * 8);
            const f16x8 bf1 = *reinterpret_cast<const f16x8*>(
                cwL + ((size_t)(16 + cs) * 64 + l) * 8);
            d0 = __builtin_amdgcn_mfma_f32_16x16x32_f16(af, bf0, d0, 0, 0, 0);
            d1 = __builtin_amdgcn_mfma_f32_16x16x32_f16(af, bf1, d1, 0, 0, 0);
            u0 = p0; u1 = p1;
        }
        xs += __shfl_xor(xs, 16);
        xs += __shfl_xor(xs, 32);
    }

    // ---- softmax: fully in-wave ----
    float wsacc0 = 0.f, wsacc1 = 0.f;
#pragma unroll
    for (int r = 0; r < 4; ++r) {
        const int rho = g * 4 + r;
        const float xsr = __shfl(xs, rho);
        const float l0 = (xsr - 2.f * d0[r] + csq0) * nsf0;
        const float l1 = (xsr - 2.f * d1[r] + csq1) * nsf1;
        const float mx = rowmax16(fmaxf(l0, l1));
        const float e0 = __expf(l0 - mx);
        const float e1 = __expf(l1 - mx);
        const float inv = 1.f / rowsum16(e0 + e1);
        const float w0 = e0 * inv, w1 = e1 * inv;
        wsacc0 += w0; wsacc1 += w1;
        wexch[(a     ) * WP + w * 16 + rho] = (f16)w0;
        wexch[(a + 16) * WP + w * 16 + rho] = (f16)w1;
    }
    wsacc0 += __shfl_xor(wsacc0, 16); wsacc0 += __shfl_xor(wsacc0, 32);
    wsacc1 += __shfl_xor(wsacc1, 16); wsacc1 += __shfl_xor(wsacc1, 32);
    if (l < 16) { wsq[w][l] = wsacc0; wsq[w][l + 16] = wsacc1; }

    __syncthreads();   // wexch/wsq ready

    // ---- wx: A[k][n] from wexch, B[n][c] gathered from global; 64 c/wave ----
    f32x4 acc[4][2];
#pragma unroll
    for (int ct = 0; ct < 4; ++ct)
#pragma unroll
        for (int kt = 0; kt < 2; ++kt) acc[ct][kt] = (f32x4){0.f, 0.f, 0.f, 0.f};

    const int c0 = w * 64;
#pragma unroll
    for (int sq2 = 0; sq2 < 4; ++sq2) {
        const f16x8 a0 = *reinterpret_cast<const f16x8*>(
            &wexch[(a     ) * WP + sq2 * 32 + g * 8]);
        const f16x8 a1 = *reinterpret_cast<const f16x8*>(
            &wexch[(a + 16) * WP + sq2 * 32 + g * 8]);
        const float* xb = x + (size_t)(b * NN + n0 + sq2 * 32 + g * 8) * CCH;
#pragma unroll
        for (int ct = 0; ct < 4; ++ct) {
            const int c = c0 + ct * 16 + a;
            f16x8 B;
#pragma unroll
            for (int i = 0; i < 8; ++i) B[i] = (f16)xb[(size_t)i * CCH + c];
            acc[ct][0] = __builtin_amdgcn_mfma_f32_16x16x32_f16(a0, B, acc[ct][0], 0, 0, 0);
            acc[ct][1] = __builtin_amdgcn_mfma_f32_16x16x32_f16(a1, B, acc[ct][1], 0, 0, 0);
        }
    }

    // ---- store partials as f16 ----
    {
        f16* pp = reinterpret_cast<f16*>(ws) +
                  ((size_t)(chunk * BB + b)) * CCH * KK;
#pragma unroll
        for (int ct = 0; ct < 4; ++ct) {
            const int c = c0 + ct * 16 + a;
#pragma unroll
            for (int kt = 0; kt < 2; ++kt) {
                const f32x4 v = acc[ct][kt];
                const f16x4 h = {(f16)v[0], (f16)v[1], (f16)v[2], (f16)v[3]};
                *reinterpret_cast<f16x4*>(
                    pp + (size_t)c * KK + kt * 16 + g * 4) = h;
            }
        }
    }
    if (t < KK) {
        float s = 0.f;
#pragma unroll
        for (int p = 0; p < 8; ++p) s += wsq[p][t];
        ws[WS_WSP + ((size_t)chunk * BB + b) * KK + t] = s;
    }
}

// ---------------------------------------------------------------------------
// Kernel R: reduce f16 partials + enc -> BN -> ReLU -> sum_k => encv
// ---------------------------------------------------------------------------
__global__ __launch_bounds__(256) void reduce_encv(
    float* __restrict__ ws, const float* __restrict__ cw,
    const float* __restrict__ gamma, const float* __restrict__ beta,
    const float* __restrict__ mean, const float* __restrict__ var)
{
    __shared__ float wsum_s[KK];
    const int b  = blockIdx.y;
    const int cs = blockIdx.x;
    const int t  = threadIdx.x;

    if (t < KK) {
        float s0 = 0.f, s1 = 0.f;
        for (int ch = 0; ch < NBLK; ch += 2) {
            s0 += ws[WS_WSP + ((size_t)(ch + 0) * BB + b) * KK + t];
            s1 += ws[WS_WSP + ((size_t)(ch + 1) * BB + b) * KK + t];
        }
        wsum_s[t] = s0 + s1;
    }
    __syncthreads();

    const int cl = t >> 3;
    const int c  = cs * 32 + cl;
    const int kq = t & 7;
    const f16* p = reinterpret_cast<const f16*>(ws) +
                   ((size_t)b * CCH + c) * KK + kq * 4;
    const size_t stride = (size_t)BB * CCH * KK;   // in f16 elems

    f32x4 a0 = {0.f, 0.f, 0.f, 0.f}, a1 = {0.f, 0.f, 0.f, 0.f};
    for (int ch = 0; ch < NBLK; ch += 2) {
        const f16x4 h0 = *reinterpret_cast<const f16x4*>(p + (ch + 0) * stride);
        const f16x4 h1 = *reinterpret_cast<const f16x4*>(p + (ch + 1) * stride);
        a0 += (f32x4){(float)h0[0], (float)h0[1], (float)h0[2], (float)h0[3]};
        a1 += (f32x4){(float)h1[0], (float)h1[1], (float)h1[2], (float)h1[3]};
    }
    const f32x4 aa = a0 + a1;

    const float g  = gamma[c] * rsqrtf(var[c] + BN_EPS);
    const float mu = mean[c];
    const float be = beta[c];
    const float4 cv = *reinterpret_cast<const float4*>(cw + c * KK + kq * 4);
    const float4 sv = *reinterpret_cast<const float4*>(&wsum_s[kq * 4]);
    float s = 0.f;
    s += fmaxf((aa[0] - cv.x * sv.x - mu) * g + be, 0.f);
    s += fmaxf((aa[1] - cv.y * sv.y - mu) * g + be, 0.f);
    s += fmaxf((aa[2] - cv.z * sv.z - mu) * g + be, 0.f);
    s += fmaxf((aa[3] - cv.w * sv.w - mu) * g + be, 0.f);
    s += __shfl_xor(s, 1);
    s += __shfl_xor(s, 2);
    s += __shfl_xor(s, 4);
    if (kq == 0) ws[WS_ENC + (size_t)b * CCH + c] = s;
}

// ---------------------------------------------------------------------------
// Kernel C: fused attn + scale (+ se in the cc==8 plane) — r19 verbatim.
// ---------------------------------------------------------------------------
__global__ __launch_bounds__(256) void scale_fused(
    const float* __restrict__ x, const float* __restrict__ enc,
    const float* __restrict__ w_enc, const float* __restrict__ b_enc,
    const float* __restrict__ w_se, const float* __restrict__ b_se,
    float* __restrict__ out)
{
    __shared__ float ev[CCH];
    __shared__ float red[4][64];
    __shared__ float attnL[64];

    const int ns = blockIdx.x;
    const int cc = blockIdx.y;
    const int b  = blockIdx.z;
    const int t  = threadIdx.x;

    if (cc == 8) {
        if (ns != 0) return;
        ev[t]       = enc[(size_t)b * CCH + t];
        ev[t + 256] = enc[(size_t)b * CCH + 256 + t];
        __syncthreads();
        if (t < 8 * CLS) {
            const int j = t >> 3, p = t & 7;
            float a = 0.f;
            for (int c = p; c < CCH; c += 8) a += ev[c] * w_se[c * CLS + j];
            a += __shfl_xor(a, 1);
            a += __shfl_xor(a, 2);
            a += __shfl_xor(a, 4);
            if (p == 0)
                out[(size_t)BB * NN * CCH + b * CLS + j] =
                    1.f / (1.f + __expf(-(a + b_se[j])));
        }
        return;
    }

    ev[t]       = enc[(size_t)b * CCH + t];
    ev[t + 256] = enc[(size_t)b * CCH + 256 + t];
    __syncthreads();

    // ---- attn head for c2 = cc*64 + (t&63); 4-way row-part split ----
    {
        const int c2 = cc * 64 + (t & 63);
        const int p  = t >> 6;
        float a0 = 0.f, a1 = 0.f, a2 = 0.f, a3 = 0.f;
#pragma unroll
        for (int i = 0; i < 128; i += 4) {
            const int c = p * 128 + i;
            a0 += ev[c + 0] * w_enc[(size_t)(c + 0) * CCH + c2];
            a1 += ev[c + 1] * w_enc[(size_t)(c + 1) * CCH + c2];
            a2 += ev[c + 2] * w_enc[(size_t)(c + 2) * CCH + c2];
            a3 += ev[c + 3] * w_enc[(size_t)(c + 3) * CCH + c2];
        }
        red[p][t & 63] = (a0 + a1) + (a2 + a3);
        __syncthreads();
        if (t < 64) {
            const float v = red[0][t] + red[1][t] + red[2][t] + red[3][t]
                          + b_enc[cc * 64 + t];
            attnL[t] = 1.f / (1.f + __expf(-v));
        }
        __syncthreads();
    }

    // ---- scale 512 rows x 64 c ----
    const int q   = t & 15;          // c-quad
    const int rr0 = t >> 4;          // row 0..15 (stride 16)
    const f32x4 av = *reinterpret_cast<const f32x4*>(attnL + q * 4);
#pragma unroll 8
    for (int i = 0; i < 32; ++i) {
        const int r = ns * 512 + i * 16 + rr0;
        const size_t off = ((size_t)(b * NN + r)) * CCH + cc * 64 + q * 4;
        const f32x4 xv = *reinterpret_cast<const f32x4*>(x + off);
        __builtin_nontemporal_store(xv * av, reinterpret_cast<f32x4*>(out + off));
    }
}

// ---------------------------------------------------------------------------
extern "C" void kernel_launch(void* const* d_in, const int* in_sizes, int n_in,
                              void* d_out, int out_size, void* d_ws, size_t ws_size,
                              hipStream_t stream)
{
    const float* x     = (const float*)d_in[0];
    const float* cw    = (const float*)d_in[1];
    const float* sf    = (const float*)d_in[2];
    const float* gamma = (const float*)d_in[3];
    const float* beta  = (const float*)d_in[4];
    const float* mean  = (const float*)d_in[5];
    const float* var   = (const float*)d_in[6];
    const float* w_enc = (const float*)d_in[7];
    const float* b_enc = (const float*)d_in[8];
    const float* w_se  = (const float*)d_in[9];
    const float* b_se  = (const float*)d_in[10];
    float* out = (float*)d_out;
    float* ws  = (float*)d_ws;

    enc_mfma<<<dim3(NBLK, BB), 512, 0, stream>>>(x, cw, sf, ws);
    reduce_encv<<<dim3(16, BB), 256, 0, stream>>>(ws, cw, gamma, beta, mean, var);
    scale_fused<<<dim3(8, 9, BB), 256, 0, stream>>>(
        x, ws + WS_ENC, w_enc, b_enc, w_se, b_se, out);
}